// Round 14
// baseline (335.996 us; speedup 1.0000x reference)
//
#include <hip/hip_runtime.h>

#define NODE_DIM 128
#define NUM_IRREPS 224
#define SPH_DIM 480
#define HIDDEN 576   // NODE_DIM + 2*NUM_IRREPS
#define NUM_BASIS 20
#define N_NODES 10000
#define N_EDGES 160000
#define NPB 4        // nodes per block in fused MLP
#define EB 16        // edges per window (block)
#define NT 36        // N-tiles (576/16)
#define IRP 233      // pair row stride in words (odd)
#define SCP 138      // scal row stride in shorts (69 words, odd)
#define SOP 577      // so_s row stride in shorts (odd)
#define PREP_BLOCKS 2048
#define MLP_BLOCKS ((N_NODES + NPB - 1) / NPB)

typedef __attribute__((ext_vector_type(8))) short short8v;   // 8 bf16
typedef __attribute__((ext_vector_type(4))) float f32x4;

__device__ __forceinline__ unsigned short f2bf(float f) {
    unsigned int u = __builtin_bit_cast(unsigned int, f);
    u = (u + 0x7fff + ((u >> 16) & 1)) >> 16;   // RNE
    return (unsigned short)u;
}
__device__ __forceinline__ float bf2f(unsigned short h) {
    unsigned int u = ((unsigned int)h) << 16;
    return __builtin_bit_cast(float, u);
}

// ---------------- fused prep + node MLP (disjoint block ranges, concurrent) ----------------
__global__ __launch_bounds__(256) void prep_mlp_kernel(
    const float* __restrict__ xs, const float* __restrict__ xsp,
    float* __restrict__ out,
    const int* __restrict__ eidx, int* __restrict__ counts,
    const float* __restrict__ Wr, unsigned short* __restrict__ bfrag,
    const float* __restrict__ W1, const float* __restrict__ b1,
    const float* __restrict__ W2, const float* __restrict__ b2,
    unsigned short* __restrict__ so_bf)
{
    const int t = threadIdx.x;
    if (blockIdx.x < PREP_BLOCKS) {
        const int stride = PREP_BLOCKS * 256;
        const int gt = blockIdx.x * 256 + t;
        for (int i = gt; i < N_NODES * NODE_DIM; i += stride) out[i] = xs[i];
        float* o2 = out + (size_t)N_NODES * NODE_DIM;
        for (int i = gt; i < N_NODES * SPH_DIM; i += stride) o2[i] = xsp[i];
        if (gt < N_EDGES) atomicAdd(&counts[eidx[gt]], 1);
        if (blockIdx.x == PREP_BLOCKS - 1) {
            for (int idx = t; idx < NT * 64; idx += 256) {
                const int nt = idx >> 6, l = idx & 63;
                const int col = nt * 16 + (l & 15);
                const int kb = (l >> 4) * 8;
                #pragma unroll
                for (int j = 0; j < 8; ++j) {
                    const int k = kb + j;
                    bfrag[(size_t)idx * 8 + j] = (k < NUM_BASIS) ? f2bf(Wr[k * HIDDEN + col]) : (unsigned short)0;
                }
            }
        }
        return;
    }
    // ---- node MLP: 256 threads, 4 nodes/block ----
    __shared__ float xsm[NPB][NODE_DIM];
    __shared__ float hsm[NPB][NODE_DIM];
    const int n0 = (blockIdx.x - PREP_BLOCKS) * NPB;
    const int half = t >> 7;
    const int tc = t & 127;

    #pragma unroll
    for (int i = 0; i < 2; ++i) {
        const int nn = 2 * half + i;
        const int node = n0 + nn;
        xsm[nn][tc] = (node < N_NODES) ? xs[(size_t)node * NODE_DIM + tc] : 0.f;
    }
    __syncthreads();

    float acc[2] = {b1[tc], b1[tc]};
    for (int k = 0; k < NODE_DIM; ++k) {
        const float w = W1[k * NODE_DIM + tc];
        #pragma unroll
        for (int i = 0; i < 2; ++i) acc[i] = fmaf(xsm[2 * half + i][k], w, acc[i]);
    }
    #pragma unroll
    for (int i = 0; i < 2; ++i) {
        const float v = acc[i];
        hsm[2 * half + i][tc] = v / (1.f + __expf(-v));
    }
    __syncthreads();

    for (int j = t; j < HIDDEN; j += 256) {
        float a2[NPB];
        #pragma unroll
        for (int n = 0; n < NPB; ++n) a2[n] = b2[j];
        for (int k = 0; k < NODE_DIM; ++k) {
            const float w = W2[k * HIDDEN + j];
            #pragma unroll
            for (int n = 0; n < NPB; ++n) a2[n] = fmaf(hsm[n][k], w, a2[n]);
        }
        #pragma unroll
        for (int n = 0; n < NPB; ++n) {
            const int node = n0 + n;
            if (node < N_NODES) so_bf[(size_t)node * HIDDEN + j] = f2bf(a2[n]);
        }
    }
}

// ---------------- CSR scan / scatter ----------------
__global__ __launch_bounds__(1024) void scan_kernel(const int* __restrict__ counts,
                                                    int* __restrict__ offsets,
                                                    int* __restrict__ cursor) {
    __shared__ int wsum[16];
    const int tid = threadIdx.x;
    int vals[10];
    int run = 0;
    #pragma unroll
    for (int i = 0; i < 10; ++i) {
        int idx = tid * 10 + i;
        int c = (idx < N_NODES) ? counts[idx] : 0;
        vals[i] = run;
        run += c;
    }
    const int lane = tid & 63, w = tid >> 6;
    int inc = run;
    #pragma unroll
    for (int off = 1; off < 64; off <<= 1) {
        int v = __shfl_up(inc, off);
        if (lane >= off) inc += v;
    }
    if (lane == 63) wsum[w] = inc;
    __syncthreads();
    if (w == 0) {
        int v = (lane < 16) ? wsum[lane] : 0;
        #pragma unroll
        for (int off = 1; off < 16; off <<= 1) {
            int u = __shfl_up(v, off);
            if (lane >= off) v += u;
        }
        if (lane < 16) wsum[lane] = v;
    }
    __syncthreads();
    const int wbase = (w > 0) ? wsum[w - 1] : 0;
    const int base = wbase + inc - run;   // exclusive prefix
    #pragma unroll
    for (int i = 0; i < 10; ++i) {
        int idx = tid * 10 + i;
        if (idx < N_NODES) {
            int v = base + vals[i];
            offsets[idx] = v;
            cursor[idx] = v;
        }
    }
    if (tid == 1023) offsets[N_NODES] = wbase + inc;
}

__global__ __launch_bounds__(256) void scatter_kernel(const int* __restrict__ eidx,
                                                      int* __restrict__ cursor,
                                                      int* __restrict__ edge_order,
                                                      int* __restrict__ edge_src) {
    int i = blockIdx.x * blockDim.x + threadIdx.x;
    if (i < N_EDGES) {
        int s = eidx[i];
        int pos = atomicAdd(&cursor[s], 1);
        edge_order[pos] = i;
        edge_src[pos] = s;
    }
}

__device__ __forceinline__ int gate_of(int d) {
    return (d < 128) ? d : (d < 320) ? (128 + (d - 128) / 3) : (192 + (d - 320) / 5);
}

// ---------------- edge MFMA kernel: 16 sorted edges/block, all-coalesced ----------------
// Phase A0: stage so rows (coalesced, 1 line/wave-instr) + rbf rows into LDS.
// Phase A: filter GEMM on matrix cores; epilogue reads so from LDS.
// Phase B: float2 xsp/rsh streams; segmented atomic flush on src change.
__global__ __launch_bounds__(256, 4) void edge_mfma(
    const float* __restrict__ xsp,
    const float* __restrict__ rbf, const float* __restrict__ fcut,
    const float* __restrict__ rsh, const int* __restrict__ eidx,
    const unsigned short* __restrict__ bfrag, const float* __restrict__ br,
    const unsigned short* __restrict__ so_bf,
    const int* __restrict__ edge_order, const int* __restrict__ edge_src,
    float* __restrict__ out_scalar, float* __restrict__ out_sph)
{
    __shared__ unsigned short so_s[EB][SOP];      // 18.5 KB (odd stride)
    __shared__ unsigned int   pair_s[EB][IRP];    // 14.9 KB
    __shared__ unsigned short scal_s[EB][SCP];    // 4.4 KB
    __shared__ float rbf_s[EB][NUM_BASIS];        // 1.25 KB
    __shared__ int   e_s[EB];
    __shared__ int   src_s[EB];
    __shared__ int   dst_s[EB];
    __shared__ float fc_s[EB];

    const int t = threadIdx.x;
    const int base = blockIdx.x * EB;
    const int lane = t & 63, w = t >> 6;

    // ---- stage meta ----
    if (t < EB) {
        int pos = base + t;
        int e = edge_order[pos];
        e_s[t]   = e;
        src_s[t] = edge_src[pos];
        dst_s[t] = eidx[N_EDGES + e];
        fc_s[t]  = fcut[e];
    }
    __syncthreads();

    // ---- phase A0: coalesced staging of so rows and rbf rows ----
    for (int i = t; i < EB * HIDDEN; i += 256) {
        const int row = i / HIDDEN, col = i - row * HIDDEN;
        so_s[row][col] = so_bf[(size_t)dst_s[row] * HIDDEN + col];
    }
    for (int i = t; i < EB * NUM_BASIS; i += 256) {
        const int row = i / NUM_BASIS, k = i - row * NUM_BASIS;
        rbf_s[row][k] = rbf[(size_t)e_s[row] * NUM_BASIS + k];
    }
    __syncthreads();

    // ---- A-fragment from LDS (lane l: edge row l&15, k=(l>>4)*8+j) ----
    const int m_row = lane & 15;
    const int kb = (lane >> 4) * 8;
    short8v a0;
    #pragma unroll
    for (int j = 0; j < 8; ++j) {
        const int k = kb + j;
        a0[j] = (k < NUM_BASIS) ? (short)f2bf(rbf_s[m_row][k]) : (short)0;
    }

    // ---- phase A: 9 N-tiles per wave ----
    {
        const int rbase = (lane >> 4) * 4;
        float fA[4];
        #pragma unroll
        for (int r = 0; r < 4; ++r) fA[r] = fc_s[rbase + r];
        #pragma unroll
        for (int i = 0; i < NT / 4; ++i) {
            const int nt = w * (NT / 4) + i;
            const short8v bf = *(const short8v*)(bfrag + (size_t)(nt * 64 + lane) * 8);
            f32x4 c0 = {0.f, 0.f, 0.f, 0.f};
            c0 = __builtin_amdgcn_mfma_f32_16x16x32_bf16(a0, bf, c0, 0, 0, 0);
            const int col = nt * 16 + (lane & 15);
            const float brc = br[col];
            #pragma unroll
            for (int r = 0; r < 4; ++r) {
                const int row = rbase + r;
                const float sov = bf2f(so_s[row][col]);
                const float v = (c0[r] + brc) * fA[r] * sov;
                const unsigned short hv = f2bf(v);
                if (col < NUM_IRREPS) {
                    ((unsigned short*)&pair_s[row][col])[0] = hv;              // state (lo)
                } else if (col < 2 * NUM_IRREPS) {
                    ((unsigned short*)&pair_s[row][col - NUM_IRREPS])[1] = hv; // edge (hi)
                } else {
                    scal_s[row][col - 2 * NUM_IRREPS] = hv;
                }
            }
        }
    }
    __syncthreads();

    // ---- phase B: float2 consume, segmented accumulate ----
    const bool sphOn = (t < 240);
    const int d0 = 2 * t;
    const int g0 = sphOn ? gate_of(d0) : 0;
    const int g1 = sphOn ? gate_of(d0 + 1) : 0;

    float accS = 0.f, accD0 = 0.f, accD1 = 0.f;
    int cur_src = src_s[0];

    #pragma unroll
    for (int le = 0; le < EB; ++le) {
        const int s = src_s[le];
        if (s != cur_src) {   // block-uniform branch
            if (sphOn) {
                atomicAdd(&out_sph[(size_t)cur_src * SPH_DIM + d0],     accD0);
                atomicAdd(&out_sph[(size_t)cur_src * SPH_DIM + d0 + 1], accD1);
            }
            if (t < 128) atomicAdd(&out_scalar[(size_t)cur_src * NODE_DIM + t], accS);
            accD0 = accD1 = accS = 0.f;
            cur_src = s;
        }
        if (sphOn) {
            const float2 xv = *(const float2*)(xsp + (size_t)dst_s[le] * SPH_DIM + d0);
            const float2 rv = *(const float2*)(rsh + (size_t)e_s[le]  * SPH_DIM + d0);
            const unsigned int p0 = pair_s[le][g0];
            const unsigned int p1 = pair_s[le][g1];
            accD0 = fmaf(xv.x, bf2f((unsigned short)(p0 & 0xffffu)),
                    fmaf(rv.x, bf2f((unsigned short)(p0 >> 16)), accD0));
            accD1 = fmaf(xv.y, bf2f((unsigned short)(p1 & 0xffffu)),
                    fmaf(rv.y, bf2f((unsigned short)(p1 >> 16)), accD1));
        }
        if (t < 128) accS += bf2f(scal_s[le][t]);
    }
    if (sphOn) {
        atomicAdd(&out_sph[(size_t)cur_src * SPH_DIM + d0],     accD0);
        atomicAdd(&out_sph[(size_t)cur_src * SPH_DIM + d0 + 1], accD1);
    }
    if (t < 128) atomicAdd(&out_scalar[(size_t)cur_src * NODE_DIM + t], accS);
}

extern "C" void kernel_launch(void* const* d_in, const int* in_sizes, int n_in,
                              void* d_out, int out_size, void* d_ws, size_t ws_size,
                              hipStream_t stream) {
    const float* x_scalar    = (const float*)d_in[0];
    const float* x_spherical = (const float*)d_in[1];
    const float* rbf         = (const float*)d_in[2];
    const float* fcut        = (const float*)d_in[3];
    const float* rsh         = (const float*)d_in[4];
    const int*   eidx        = (const int*)d_in[5];
    const float* W1          = (const float*)d_in[6];
    const float* b1          = (const float*)d_in[7];
    const float* W2          = (const float*)d_in[8];
    const float* b2          = (const float*)d_in[9];
    const float* Wr          = (const float*)d_in[10];
    const float* br          = (const float*)d_in[11];

    float* out        = (float*)d_out;
    float* out_scalar = out;                                   // (N_NODES, 128)
    float* out_sph    = out + (size_t)N_NODES * NODE_DIM;      // (N_NODES, 480)

    // workspace layout
    unsigned short* so_bf   = (unsigned short*)d_ws;           // 10000*576 bf16
    int*   counts     = (int*)(so_bf + (size_t)N_NODES * HIDDEN);
    int*   offsets    = counts + N_NODES;                      // 10001
    int*   cursor     = offsets + N_NODES + 1;                 // 10000
    int*   edge_order = cursor + N_NODES;                      // 160000
    int*   edge_src   = edge_order + N_EDGES;                  // 160000
    unsigned short* bfrag = (unsigned short*)((((uintptr_t)(edge_src + N_EDGES)) + 15) & ~(uintptr_t)15);

    hipMemsetAsync(counts, 0, N_NODES * sizeof(int), stream);
    prep_mlp_kernel<<<PREP_BLOCKS + MLP_BLOCKS, 256, 0, stream>>>(
        x_scalar, x_spherical, out, eidx, counts, Wr, bfrag,
        W1, b1, W2, b2, so_bf);
    scan_kernel<<<1, 1024, 0, stream>>>(counts, offsets, cursor);
    scatter_kernel<<<(N_EDGES + 255) / 256, 256, 0, stream>>>(eidx, cursor, edge_order, edge_src);
    edge_mfma<<<N_EDGES / EB, 256, 0, stream>>>(x_spherical, rbf, fcut, rsh, eidx,
                                                bfrag, br, so_bf, edge_order, edge_src,
                                                out_scalar, out_sph);
}